// Round 1
// baseline (289.495 us; speedup 1.0000x reference)
//
#include <hip/hip_runtime.h>
#include <hip/hip_bf16.h>

// out[i] = probs[X[i,0]*125000 + X[i,1]*2500 + X[i,2]*50 + X[i,3]]
// probs: 50^4 = 6,250,000 float32 (25 MB) — fits in L3, mostly in L2.
// X: [N,4] int32, row-contiguous -> one int4 load per thread (16 B/lane, coalesced).
__global__ __launch_bounds__(256) void jc_gather_kernel(
    const int4* __restrict__ X,
    const float* __restrict__ probs,
    float* __restrict__ out,
    int n)
{
    int i = blockIdx.x * blockDim.x + threadIdx.x;
    if (i < n) {
        int4 x = X[i];
        // strides for shape (50,50,50,50): 125000, 2500, 50, 1
        int idx = x.x * 125000 + x.y * 2500 + x.z * 50 + x.w;
        out[i] = probs[idx];
    }
}

extern "C" void kernel_launch(void* const* d_in, const int* in_sizes, int n_in,
                              void* d_out, int out_size, void* d_ws, size_t ws_size,
                              hipStream_t stream) {
    const float* probs = (const float*)d_in[0];
    const int4*  X     = (const int4*)d_in[1];   // in_sizes[1] = N*4 int32
    float* out = (float*)d_out;

    int n = out_size;  // 8,000,000 samples
    int block = 256;
    int grid = (n + block - 1) / block;
    jc_gather_kernel<<<grid, block, 0, stream>>>(X, probs, out, n);
}